// Round 16
// baseline (755.451 us; speedup 1.0000x reference)
//
#include <hip/hip_runtime.h>
#include <stdint.h>

#define NN 100000
#define NE 3200000
#define KIN 512
#define HID 256
#define NOUT 40
#define NB2 1024      // fine col-buckets (col >> 7); 782 used
#define BSHIFT2 7
#define NBKT 782      // ceil(NN/128)
#define EPB 8192      // edges per block in bucket pass

typedef __attribute__((ext_vector_type(8))) __bf16 bf16x8;
typedef __attribute__((ext_vector_type(4))) float f32x4;

__device__ __forceinline__ float b2f(unsigned short u) {
  union { unsigned int i; float f; } x; x.i = ((unsigned int)u) << 16; return x.f;
}
__device__ __forceinline__ unsigned short f2b(float f) {
  unsigned int i = __float_as_uint(f);
  return (unsigned short)((i + 0x7FFFu + ((i >> 16) & 1u)) >> 16);
}
__device__ __forceinline__ float uf(unsigned int x) { return __uint_as_float(x); }
// custom e4m4 (non-negative): u = ((e32-120)<<4)|m4; decode val = uf(u<<19) * 2^120.
// No denormal bit patterns: codes 1..15 never emitted (flush-to-zero below 2^-6 at encode).
// Exact e4m4 -> bf16: u ? (u<<3)+0x3C00 : 0.
__device__ __forceinline__ unsigned char f2e8(float v) {
  v = fminf(v, 480.f);
  unsigned int ui = __float_as_uint(v);
  ui += 0x3FFFFu + ((ui >> 19) & 1u);  // RNE at 4 mantissa bits
  unsigned int e32 = ui >> 23;
  if (e32 <= 120u) return 0;
  return (unsigned char)(((e32 - 120u) << 4) | ((ui >> 19) & 15u));
}
__device__ __forceinline__ float e82f(unsigned char u) {
  return __uint_as_float(((unsigned int)u) << 19) * 0x1p120f;
}
__device__ __forceinline__ unsigned short e82b(unsigned char u) {
  return u ? (unsigned short)(((unsigned int)u << 3) + 0x3C00u) : (unsigned short)0;
}
// XOR-swizzled LDS address for [row][32] bf16 tiles (row stride 64B).
__device__ __forceinline__ unsigned short* swz(unsigned short* base, int row, int kk) {
  int byte = (row * 64 + kk * 2) ^ ((row & 7) << 4);
  return (unsigned short*)((char*)base + byte);
}
// XOR-swizzled staging address for [row][64] bf16 tiles (row stride 128B); cb = byte in row.
__device__ __forceinline__ char* swzst(unsigned short* base, int row, int cb) {
  int byte = (row * 128 + cb) ^ ((row & 7) << 4);
  return (char*)base + byte;
}

// ---------------- fine-bucketed CSR build (128-col buckets) ----------------
__global__ __launch_bounds__(256) void k_bhist(const int* __restrict__ ecol, int* __restrict__ bcnt) {
  __shared__ int hist[NB2];
  int t = threadIdx.x;
  for (int j = t; j < NB2; j += 256) hist[j] = 0;
  __syncthreads();
  int e0 = blockIdx.x * EPB, e1 = min(e0 + EPB, NE);
  for (int e = e0 + t; e < e1; e += 256) atomicAdd(&hist[ecol[e] >> BSHIFT2], 1);
  __syncthreads();
  for (int j = t; j < NB2; j += 256) if (hist[j]) atomicAdd(&bcnt[j], hist[j]);
}

// exclusive scan of 1024 bucket counts (single 256-thread block, 4 per thread)
__global__ void k_bscan(const int* __restrict__ bcnt, int* __restrict__ bbase, int* __restrict__ cursor) {
  __shared__ int wsum[4];
  int t = threadIdx.x, lane = t & 63, w = t >> 6;
  int4 v = *(const int4*)(bcnt + 4 * t);
  int tot = v.x + v.y + v.z + v.w;
  int s = tot;
  for (int d = 1; d < 64; d <<= 1) { int o = __shfl_up(s, d, 64); if (lane >= d) s += o; }
  if (lane == 63) wsum[w] = s;
  __syncthreads();
  int add = 0;
  for (int i = 0; i < 4; ++i) add += (i < w) ? wsum[i] : 0;
  int excl = add + s - tot;
  int p0 = excl, p1 = p0 + v.x, p2 = p1 + v.y, p3 = p2 + v.z;
  bbase[4 * t] = p0; bbase[4 * t + 1] = p1; bbase[4 * t + 2] = p2; bbase[4 * t + 3] = p3;
  cursor[4 * t] = p0; cursor[4 * t + 1] = p1; cursor[4 * t + 2] = p2; cursor[4 * t + 3] = p3;
}

// place edges into fine-bucketed u32 buffer: (col&127)<<17 | row
__global__ __launch_bounds__(256) void k_bucket(const int* __restrict__ erow, const int* __restrict__ ecol,
                                                int* __restrict__ cursor, unsigned int* __restrict__ ebuf) {
  __shared__ int hist[NB2];
  __shared__ int base[NB2];
  int t = threadIdx.x;
  for (int j = t; j < NB2; j += 256) hist[j] = 0;
  __syncthreads();
  int e0 = blockIdx.x * EPB, e1 = min(e0 + EPB, NE);
  for (int e = e0 + t; e < e1; e += 256) atomicAdd(&hist[ecol[e] >> BSHIFT2], 1);
  __syncthreads();
  for (int j = t; j < NB2; j += 256) {
    int c = hist[j];
    base[j] = (c > 0) ? atomicAdd(&cursor[j], c) : 0;
    hist[j] = 0;  // reuse as local rank cursor
  }
  __syncthreads();
  for (int e = e0 + t; e < e1; e += 256) {
    int col = ecol[e];
    int b = col >> BSHIFT2;
    int r = atomicAdd(&hist[b], 1);
    ebuf[(size_t)base[b] + r] = ((unsigned int)(col & 127) << 17) | (unsigned int)erow[e];
  }
}

// per-bucket col-degree histogram (128 cols) -> deg, dn
__global__ __launch_bounds__(256) void k_subdeg(const unsigned int* __restrict__ ebuf,
                                                const int* __restrict__ bbase, const int* __restrict__ bcnt,
                                                int* __restrict__ deg, float* __restrict__ dn) {
  __shared__ int h[128];
  int t = threadIdx.x, b = blockIdx.x;
  if (t < 128) h[t] = 0;
  __syncthreads();
  int s = bbase[b], e = s + bcnt[b];
  for (int i = s + t; i < e; i += 256) atomicAdd(&h[ebuf[i] >> 17], 1);
  __syncthreads();
  if (t < 128) {
    int col = (b << BSHIFT2) + t;
    if (col < NN) { int d = h[t]; deg[col] = d; dn[col] = d > 0 ? rsqrtf((float)d) : 0.f; }
  }
}

#define SCAN_CH 1024
__global__ void k_scan_part(const int* __restrict__ deg, int* __restrict__ partials) {
  __shared__ int lds[4];
  int b = blockIdx.x, t = threadIdx.x;
  int base = b * SCAN_CH;
  int s = 0;
  for (int j = 0; j < 4; ++j) { int i = base + t + 256 * j; if (i < NN) s += deg[i]; }
  for (int d = 32; d > 0; d >>= 1) s += __shfl_down(s, d, 64);
  int lane = t & 63, w = t >> 6;
  if (lane == 0) lds[w] = s;
  __syncthreads();
  if (t == 0) partials[b] = lds[0] + lds[1] + lds[2] + lds[3];
}

__global__ void k_scan_partials(int* __restrict__ partials, int nb) {
  __shared__ int lds[2];
  int t = threadIdx.x;  // 128 threads, nb <= 128
  int v = (t < nb) ? partials[t] : 0;
  int lane = t & 63, w = t >> 6;
  int s = v;
  for (int d = 1; d < 64; d <<= 1) { int o = __shfl_up(s, d, 64); if (lane >= d) s += o; }
  if (lane == 63) lds[w] = s;
  __syncthreads();
  int base = (w == 1) ? lds[0] : 0;
  if (t < nb) partials[t] = base + s - v;  // exclusive
}

__global__ void k_scan_final(const int* __restrict__ deg, const int* __restrict__ partials,
                             int* __restrict__ colptr, int* __restrict__ pos) {
  __shared__ int lds[4];
  int b = blockIdx.x, t = threadIdx.x;
  int base = b * SCAN_CH + t * 4;
  int d0 = (base + 0 < NN) ? deg[base + 0] : 0;
  int d1 = (base + 1 < NN) ? deg[base + 1] : 0;
  int d2 = (base + 2 < NN) ? deg[base + 2] : 0;
  int d3 = (base + 3 < NN) ? deg[base + 3] : 0;
  int tot = d0 + d1 + d2 + d3;
  int lane = t & 63, w = t >> 6;
  int s = tot;
  for (int d = 1; d < 64; d <<= 1) { int o = __shfl_up(s, d, 64); if (lane >= d) s += o; }
  if (lane == 63) lds[w] = s;
  __syncthreads();
  int wbase = 0;
  for (int i = 0; i < 4; ++i) wbase += (i < w) ? lds[i] : 0;
  int excl = wbase + s - tot + partials[b];
  int p0 = excl, p1 = p0 + d0, p2 = p1 + d1, p3 = p2 + d2, p4 = p3 + d3;
  if (base + 0 <= NN) colptr[base + 0] = p0;
  if (base + 1 <= NN) colptr[base + 1] = p1;
  if (base + 2 <= NN) colptr[base + 2] = p2;
  if (base + 3 <= NN) colptr[base + 3] = p3;
  if (base + 4 == NN) colptr[NN] = p4;
  if (base + 0 < NN) pos[base + 0] = p0;
  if (base + 1 < NN) pos[base + 1] = p1;
  if (base + 2 < NN) pos[base + 2] = p2;
  if (base + 3 < NN) pos[base + 3] = p3;
}

// per-bucket fill: pos atomics hit a 512B window, csr_row writes a ~16KB L2-resident window
__global__ __launch_bounds__(256) void k_fill2(const unsigned int* __restrict__ ebuf,
                                               const int* __restrict__ bbase, const int* __restrict__ bcnt,
                                               int* __restrict__ pos, int* __restrict__ csr_row) {
  int b = blockIdx.x >> 2, sub = blockIdx.x & 3;
  int s = bbase[b], e = s + bcnt[b];
  int cb = b << BSHIFT2;
  for (int i = s + sub * 256 + threadIdx.x; i < e; i += 1024) {
    unsigned int pk = ebuf[i];
    int p = atomicAdd(&pos[cb | (int)(pk >> 17)], 1);
    csr_row[p] = (int)(pk & 0x1FFFF);
  }
}

// ---------------- weight prep (+ zero sentinel row NN of h0s) ----------------
__global__ void k_prep(const float* __restrict__ fc0_W, const float* __restrict__ fc0_b,
                       const float* __restrict__ conv_W, const float* __restrict__ conv_b,
                       const float* __restrict__ bn_gamma, const float* __restrict__ bn_beta,
                       const float* __restrict__ bn_mean, const float* __restrict__ bn_var,
                       const float* __restrict__ clf_W,
                       unsigned short* __restrict__ W0t, unsigned short* __restrict__ Wct,
                       unsigned short* __restrict__ Wclft,
                       float* __restrict__ epia, float* __restrict__ epib,
                       unsigned char* __restrict__ h0s) {
  int idx = blockIdx.x * 256 + threadIdx.x;
  if (idx < 131072) {                       // W0t[n*512+k] = fc0_W[k][n]
    int n = idx >> 9, k = idx & 511;
    W0t[idx] = f2b(fc0_W[k * 256 + n]);
  } else if (idx < 262144) {                // Wct[l][n*256+k] = conv_W[l][k][n]
    int j = idx - 131072;
    int l = j >> 16, rem = j & 65535, n = rem >> 8, k = rem & 255;
    Wct[j] = f2b(conv_W[l * 65536 + k * 256 + n]);
  } else if (idx < 262144 + 48 * 256) {     // Wclft[n*256+k], rows 40..47 zero
    int j = idx - 262144;
    int n = j >> 8, k = j & 255;
    Wclft[j] = f2b(n < NOUT ? clf_W[k * NOUT + n] : 0.f);
  } else if (idx < 262144 + 12288 + 768) {  // epilogue constants per BN layer
    int j = idx - 262144 - 12288;           // layer*256 + c
    int layer = j >> 8, c = j & 255;
    float a = bn_gamma[j] * rsqrtf(bn_var[j] + 1e-5f);
    float bias = (layer == 0) ? fc0_b[c] : conv_b[(layer - 1) * 256 + c];
    epia[j] = a;
    epib[j] = bn_beta[j] + (bias - bn_mean[j]) * a;
  } else if (idx < 262144 + 12288 + 768 + 256) {  // zero gather-sink row NN (e4m4)
    int c = idx - (262144 + 12288 + 768);
    h0s[(size_t)NN * HID + c] = 0;
  }
}

// ---------------- MFMA GEMM, 128x256 tile, 8 waves (4x2), 2-deep pipelined K-loop ----------
// Reg-staged loads, prefetch distance 2: loads for step k+2 issue after step k's sync, giving
// each load ~2 iterations of MFMA+barrier time to land before its ds_write consumes it.
// The lgkm-only barrier does NOT drain vmcnt, so in-flight loads survive across it.
// ALAY: 0 = f32 A, 2 = e4m4 A.
// EPI 0 (fc0):    stage y=relu(a*acc+b); store h0s=e4m4(dn*y); fused clf partial outv=y@Wclft
// EPI 1 (conv0):  stage y*dn; store outv=e4m4(y*dn + decode(prev e4m4)) (in-place h0s->h1s)
// EPI 4 (conv1):  stage y; fused clf: outv = y@Wclft + prevv(outP) + clfb (f32)
template <int K, int ALAY, int EPI>
__global__ __launch_bounds__(512) void k_gemm2(const void* __restrict__ Av,
                                               const unsigned short* __restrict__ Bt,
                                               const float* __restrict__ epia,
                                               const float* __restrict__ epib,
                                               const void* prevv,
                                               const float* __restrict__ dnp,
                                               const unsigned short* __restrict__ clfW,
                                               const float* __restrict__ clfb,
                                               void* outv, void* outv2) {
  __shared__ unsigned short ldsA[128 * 32];  // 8KB
  __shared__ unsigned short ldsB[256 * 32];  // 16KB; reused as 128x64 bf16 stage in epilogue
  constexpr bool DOCLF = (EPI == 0 || EPI == 4);
  const int t = threadIdx.x;
  const int w = t >> 6, lane = t & 63;
  const int lo = lane & 15, hi = lane >> 4;
  const int wr = w >> 1, wc = w & 1;
  const int m0 = blockIdx.x * 128;
  constexpr int NK = K / 32;
  f32x4 acc[2][8];
#pragma unroll
  for (int m = 0; m < 2; ++m)
#pragma unroll
    for (int f = 0; f < 8; ++f) acc[m][f] = (f32x4){0.f, 0.f, 0.f, 0.f};

  const int arow = t >> 2;       // 0..127
  const int akk = (t & 3) * 8;   // element offset in K-step
  const int rg = m0 + arow;
  const int bn0 = t >> 2, bn1 = bn0 + 128;

  // 2-deep register stage (static [s_] indices: loop fully unrolled)
  float4 rv0[2], rv1[2];
  int4 ra[2];
  uint2 rae[2];
  int4 rb0[2], rb1[2];

#define LOADG(s_, k0_) {                                                        \
    if (ALAY == 0) {                                                            \
      const float* A = (const float*)Av;                                        \
      rv0[s_] = (float4){0.f, 0.f, 0.f, 0.f}; rv1[s_] = rv0[s_];                \
      if (rg < NN) {                                                            \
        rv0[s_] = *(const float4*)(A + (size_t)rg * K + (k0_) + akk);           \
        rv1[s_] = *(const float4*)(A + (size_t)rg * K + (k0_) + akk + 4);       \
      }                                                                         \
    } else {                                                                    \
      const unsigned char* A = (const unsigned char*)Av;                        \
      rae[s_] = (uint2){0u, 0u};                                                \
      if (rg < NN) rae[s_] = *(const uint2*)(A + (size_t)rg * K + (k0_) + akk); \
    }                                                                           \
    rb0[s_] = *(const int4*)(Bt + (size_t)bn0 * K + (k0_) + akk);               \
    rb1[s_] = *(const int4*)(Bt + (size_t)bn1 * K + (k0_) + akk);               \
  }
#define WRITELDS(s_) {                                                          \
    if (ALAY == 0) {                                                            \
      union { unsigned short u[8]; int4 v; } pk;                                \
      pk.u[0] = f2b(rv0[s_].x); pk.u[1] = f2b(rv0[s_].y);                       \
      pk.u[2] = f2b(rv0[s_].z); pk.u[3] = f2b(rv0[s_].w);                       \
      pk.u[4] = f2b(rv1[s_].x); pk.u[5] = f2b(rv1[s_].y);                       \
      pk.u[6] = f2b(rv1[s_].z); pk.u[7] = f2b(rv1[s_].w);                       \
      *(int4*)(void*)swz(ldsA, arow, akk) = pk.v;                               \
    } else {                                                                    \
      union { unsigned char b[8]; uint2 v2; } in; in.v2 = rae[s_];              \
      union { unsigned short u[8]; int4 v; } pk;                                \
      _Pragma("unroll") for (int q = 0; q < 8; ++q) pk.u[q] = e82b(in.b[q]);    \
      *(int4*)(void*)swz(ldsA, arow, akk) = pk.v;                               \
    }                                                                           \
    *(int4*)(void*)swz(ldsB, bn0, akk) = rb0[s_];                               \
    *(int4*)(void*)swz(ldsB, bn1, akk) = rb1[s_];                               \
  }

  LOADG(0, 0);
  if (NK > 1) LOADG(1, 32);
#pragma unroll
  for (int k = 0; k < NK; ++k) {
    // barrier A: all waves done reading LDS (lgkm only -- in-flight gloads survive)
    asm volatile("s_waitcnt lgkmcnt(0)" ::: "memory");
    __builtin_amdgcn_s_barrier();
    __builtin_amdgcn_sched_barrier(0);
    WRITELDS(k & 1);
    __syncthreads();
    if (k + 2 < NK) LOADG(k & 1, (k + 2) * 32);
    bf16x8 af0 = *(const bf16x8*)(void*)swz(ldsA, wr * 32 + lo, hi * 8);
    bf16x8 af1 = *(const bf16x8*)(void*)swz(ldsA, wr * 32 + 16 + lo, hi * 8);
#pragma unroll
    for (int f = 0; f < 8; ++f) {
      bf16x8 bf = *(const bf16x8*)(void*)swz(ldsB, wc * 128 + f * 16 + lo, hi * 8);
      acc[0][f] = __builtin_amdgcn_mfma_f32_16x16x32_bf16(af0, bf, acc[0][f], 0, 0, 0);
      acc[1][f] = __builtin_amdgcn_mfma_f32_16x16x32_bf16(af1, bf, acc[1][f], 0, 0, 0);
    }
  }
  // final barrier before epilogue stage reuse of ldsB
  asm volatile("s_waitcnt lgkmcnt(0)" ::: "memory");
  __builtin_amdgcn_s_barrier();
  __builtin_amdgcn_sched_barrier(0);

  f32x4 accclf[3];
#pragma unroll
  for (int f = 0; f < 3; ++f) accclf[f] = (f32x4){0.f, 0.f, 0.f, 0.f};

  // ---- staged epilogue: 4 chunks of 64 columns ----
#pragma unroll
  for (int cc = 0; cc < 4; ++cc) {
    if (cc) __syncthreads();  // protect stage reuse
    if (wc == (cc >> 1)) {
#pragma unroll
      for (int m = 0; m < 2; ++m) {
        const int rb = wr * 32 + m * 16 + hi * 4;
#pragma unroll
        for (int fl = 0; fl < 4; ++fl) {
          const int f = (cc & 1) * 4 + fl;
          const int c = wc * 128 + f * 16 + lo;  // global column
          float a_ = epia[c], b_ = epib[c];
#pragma unroll
          for (int j = 0; j < 4; ++j) {
            int row = rb + j;
            int r = m0 + row;
            float y = fmaxf(a_ * acc[m][f][j] + b_, 0.f);
            float sv;
            if constexpr (EPI == 1) {
              float dnv = (r < NN) ? dnp[r] : 0.f;
              sv = y * dnv;
            } else {
              sv = y;
            }
            *(unsigned short*)swzst(ldsB, row, (fl * 16 + lo) * 2) = f2b(sv);
          }
        }
      }
    }
    __syncthreads();
    // coalesced store phase (EPI 0: e4m4 scaled; EPI 1: e4m4 + prev; EPI 4: none)
    if constexpr (EPI == 0 || EPI == 1) {
#pragma unroll
      for (int pass = 0; pass < 2; ++pass) {
        int rr = pass * 64 + (t >> 3);
        int r = m0 + rr;
        int cb = (t & 7) * 16;
        uint4 v = *(const uint4*)swzst(ldsB, rr, cb);
        if (r < NN) {
          size_t gix = (size_t)r * HID + cc * 64 + (t & 7) * 8;
          union { unsigned short u[8]; uint4 v4; } sb; sb.v4 = v;
          if constexpr (EPI == 0) {
            float d = dnp[r];
            union { unsigned char b[8]; uint2 v2; } o8;
#pragma unroll
            for (int q = 0; q < 8; ++q) o8.b[q] = f2e8(d * b2f(sb.u[q]));
            *(uint2*)((unsigned char*)outv2 + gix) = o8.v2;
          } else {
            union { unsigned char b[8]; uint2 v2; } pv;
            pv.v2 = *(const uint2*)((const unsigned char*)prevv + gix);
            union { unsigned char b[8]; uint2 v2; } o8;
#pragma unroll
            for (int q = 0; q < 8; ++q) o8.b[q] = f2e8(b2f(sb.u[q]) + e82f(pv.b[q]));
            *(uint2*)((unsigned char*)outv + gix) = o8.v2;
          }
        }
      }
    }
    // fused classifier MFMAs on the staged chunk (K-slice = cols cc*64..cc*64+63)
    if constexpr (DOCLF) {
#pragma unroll
      for (int kk = 0; kk < 2; ++kk) {
        bf16x8 af = *(const bf16x8*)(const void*)swzst(ldsB, w * 16 + lo, (kk * 32 + hi * 8) * 2);
#pragma unroll
        for (int f = 0; f < 3; ++f) {
          bf16x8 bf = *(const bf16x8*)(clfW + (size_t)(f * 16 + lo) * HID + cc * 64 + kk * 32 + hi * 8);
          accclf[f] = __builtin_amdgcn_mfma_f32_16x16x32_bf16(af, bf, accclf[f], 0, 0, 0);
        }
      }
    }
  }
  if constexpr (DOCLF) {
    // clf write: wave w owns rows m0+w*16.., C/D layout col=lo, row=hi*4+j
#pragma unroll
    for (int f = 0; f < 3; ++f) {
      int c = f * 16 + lo;
      if (c < NOUT) {
#pragma unroll
        for (int j = 0; j < 4; ++j) {
          int r = m0 + w * 16 + hi * 4 + j;
          if (r < NN) {
            if constexpr (EPI == 0) {
              ((float*)outv)[(size_t)r * NOUT + c] = accclf[f][j];
            } else {
              ((float*)outv)[(size_t)r * NOUT + c] =
                  accclf[f][j] + ((const float*)prevv)[(size_t)r * NOUT + c] + clfb[c];
            }
          }
        }
      }
    }
  }
#undef LOADG
#undef WRITELDS
}

// ---------------- aggregation: 3-stage pipelined paired-edge e4m4 gather ----------------
// wave = 1 node. Lanes 0-31: even edges, 32-63: odd edges; 8B = 8 feats/lane (256B/row).
// Decode: raw += uf((byte<<19)&0x07F80000); final scale by dn[i]*2^120. Output e4m4.
__global__ __launch_bounds__(256) void k_agg(const int* __restrict__ colptr,
                                             const int* __restrict__ csr,
                                             const float* __restrict__ dn,
                                             const unsigned char* __restrict__ hs,
                                             unsigned char* __restrict__ X) {
  int w = threadIdx.x >> 6, lane = threadIdx.x & 63;
  int i = blockIdx.x * 4 + w;
  int hl = lane & 31, half = lane >> 5;
  const unsigned char* hb = hs + hl * 8;
  int e0 = colptr[i], e1 = colptr[i + 1];
  float a0 = 0, a1 = 0, a2 = 0, a3 = 0, a4 = 0, a5 = 0, a6 = 0, a7 = 0;
  int rA[4], rB[4];
  uint2 vA[4], vB[4];

#define LOADIDX(e_, r_) { \
  _Pragma("unroll") for (int u = 0; u < 4; ++u) { \
    int ee = (e_) + 2 * u + half; \
    int rr = csr[ee]; \
    r_[u] = (ee < e1) ? rr : NN; } }
#define GATHER(r_, v_) { \
  _Pragma("unroll") for (int u = 0; u < 4; ++u) \
    v_[u] = *(const uint2*)(hb + (size_t)r_[u] * HID); }
#define ACCUM(v_) { \
  _Pragma("unroll") for (int u = 0; u < 4; ++u) { \
    a0 += uf((v_[u].x << 19) & 0x07F80000u); a1 += uf((v_[u].x << 11) & 0x07F80000u); \
    a2 += uf((v_[u].x << 3)  & 0x07F80000u); a3 += uf((v_[u].x >> 5)  & 0x07F80000u); \
    a4 += uf((v_[u].y << 19) & 0x07F80000u); a5 += uf((v_[u].y << 11) & 0x07F80000u); \
    a6 += uf((v_[u].y << 3)  & 0x07F80000u); a7 += uf((v_[u].y >> 5)  & 0x07F80000u); } }

  int nb = (e1 - e0 + 7) >> 3;
  if (nb == 1) {
    LOADIDX(e0, rA); GATHER(rA, vA); ACCUM(vA);
  } else if (nb > 1) {
    LOADIDX(e0, rA);
    GATHER(rA, vA);
    LOADIDX(e0 + 8, rB);
    int b = 1, e = e0 + 8;
    for (; b + 1 < nb; ++b, e += 8) {
      if (b & 1) { GATHER(rB, vB); LOADIDX(e + 8, rA); ACCUM(vA); }
      else       { GATHER(rA, vA); LOADIDX(e + 8, rB); ACCUM(vB); }
    }
    if (b & 1) { GATHER(rB, vB); ACCUM(vA); ACCUM(vB); }
    else       { GATHER(rA, vA); ACCUM(vB); ACCUM(vA); }
  }
  // merge even/odd halves (lane ^ 32 holds same features)
  a0 += __shfl_xor(a0, 32); a1 += __shfl_xor(a1, 32);
  a2 += __shfl_xor(a2, 32); a3 += __shfl_xor(a3, 32);
  a4 += __shfl_xor(a4, 32); a5 += __shfl_xor(a5, 32);
  a6 += __shfl_xor(a6, 32); a7 += __shfl_xor(a7, 32);
  if (half == 0) {
    float d = dn[i] * 0x1p120f;  // fold e4m4 rescale into dn
    union { unsigned char b[8]; uint2 v; } o;
    o.b[0] = f2e8(d * a0); o.b[1] = f2e8(d * a1); o.b[2] = f2e8(d * a2); o.b[3] = f2e8(d * a3);
    o.b[4] = f2e8(d * a4); o.b[5] = f2e8(d * a5); o.b[6] = f2e8(d * a6); o.b[7] = f2e8(d * a7);
    *(uint2*)(X + (size_t)i * HID + hl * 8) = o.v;
  }
}

extern "C" void kernel_launch(void* const* d_in, const int* in_sizes, int n_in,
                              void* d_out, int out_size, void* d_ws, size_t ws_size,
                              hipStream_t stream) {
  const float* x        = (const float*)d_in[0];
  const int*   edge     = (const int*)d_in[1];
  const int*   erow     = edge;
  const int*   ecol     = edge + NE;
  const float* fc0_W    = (const float*)d_in[2];
  const float* fc0_b    = (const float*)d_in[3];
  const float* conv_W   = (const float*)d_in[4];
  const float* conv_b   = (const float*)d_in[5];
  const float* bn_gamma = (const float*)d_in[6];
  const float* bn_beta  = (const float*)d_in[7];
  const float* bn_mean  = (const float*)d_in[8];
  const float* bn_var   = (const float*)d_in[9];
  const float* clf_W    = (const float*)d_in[10];
  const float* clf_b    = (const float*)d_in[11];

  char* p = (char*)d_ws;
  auto alloc = [&](size_t bytes) { char* r = p; p += (bytes + 255) & ~(size_t)255; return r; };
  int*   deg      = (int*)alloc((size_t)NN * 4);
  float* dn       = (float*)alloc((size_t)NN * 4);
  int*   colptr   = (int*)alloc((size_t)(NN + 1) * 4);
  int*   pos      = (int*)alloc((size_t)NN * 4);
  int*   partials = (int*)alloc(1024);
  int*   bcnt     = (int*)alloc(NB2 * 4);
  int*   bbase    = (int*)alloc(NB2 * 4);
  int*   cursor   = (int*)alloc(NB2 * 4);
  int*   csr_row  = (int*)alloc(((size_t)NE + 16) * 4);
  unsigned short* W0t   = (unsigned short*)alloc((size_t)256 * 512 * 2);
  unsigned short* Wct   = (unsigned short*)alloc((size_t)2 * 256 * 256 * 2);
  unsigned short* Wclft = (unsigned short*)alloc((size_t)48 * 256 * 2);
  float* epia = (float*)alloc(768 * 4);
  float* epib = (float*)alloc(768 * 4);
  float* outP = (float*)alloc((size_t)NN * NOUT * 4);                      // clf partial h0@W
  unsigned char*  h0s = (unsigned char*)alloc((size_t)(NN + 1) * HID);     // e4m4 (+zero row NN); becomes h1s
  unsigned char*  X   = (unsigned char*)alloc((size_t)NN * HID);           // agg output (e4m4)
  unsigned int* ebuf = (unsigned int*)X;  // alias: ebuf (12.8MB) dead before X (25.6MB) first written

  int nbBlk = (NE + EPB - 1) / EPB;  // 391
  hipMemsetAsync(bcnt, 0, NB2 * 4, stream);
  k_bhist<<<nbBlk, 256, 0, stream>>>(ecol, bcnt);
  k_bscan<<<1, 256, 0, stream>>>(bcnt, bbase, cursor);
  k_bucket<<<nbBlk, 256, 0, stream>>>(erow, ecol, cursor, ebuf);
  k_subdeg<<<NBKT, 256, 0, stream>>>(ebuf, bbase, bcnt, deg, dn);
  int nb = (NN + SCAN_CH - 1) / SCAN_CH;  // 98
  k_scan_part<<<nb, 256, 0, stream>>>(deg, partials);
  k_scan_partials<<<1, 128, 0, stream>>>(partials, nb);
  k_scan_final<<<nb, 256, 0, stream>>>(deg, partials, colptr, pos);
  k_fill2<<<NBKT * 4, 256, 0, stream>>>(ebuf, bbase, bcnt, pos, csr_row);
  k_prep<<<1076, 256, 0, stream>>>(fc0_W, fc0_b, conv_W, conv_b, bn_gamma, bn_beta,
                                   bn_mean, bn_var, clf_W, W0t, Wct, Wclft, epia, epib, h0s);

  int gm2 = (NN + 127) / 128;  // 782
  // fc0 + BN0 + ReLU -> h0s (e4m4, dn-scaled) + outP = h0@Wclft (f32)
  k_gemm2<KIN, 0, 0><<<gm2, 512, 0, stream>>>(x, W0t, epia, epib, nullptr, dn, Wclft, nullptr, outP, h0s);
  // layer 0: agg(h0s) -> X (e4m4); gemm: scaled residual, in-place h0s -> h1s (e4m4)
  k_agg<<<(NN + 3) / 4, 256, 0, stream>>>(colptr, csr_row, dn, h0s, X);
  k_gemm2<HID, 2, 1><<<gm2, 512, 0, stream>>>(X, Wct, epia + 256, epib + 256, h0s, dn, nullptr, nullptr, h0s, nullptr);
  // layer 1: agg(h1s) -> X (e4m4); gemm: fused clf -> out = y@Wclft + outP + clf_b
  k_agg<<<(NN + 3) / 4, 256, 0, stream>>>(colptr, csr_row, dn, h0s, X);
  k_gemm2<HID, 2, 4><<<gm2, 512, 0, stream>>>(X, Wct + 65536, epia + 512, epib + 512, outP, nullptr, Wclft, clf_b, d_out, nullptr);
}

// Round 17
// 621.308 us; speedup vs baseline: 1.2159x; 1.2159x over previous
//
#include <hip/hip_runtime.h>
#include <stdint.h>

#define NN 100000
#define NE 3200000
#define KIN 512
#define HID 256
#define NOUT 40
#define NB2 1024      // fine col-buckets (col >> 7); 782 used
#define BSHIFT2 7
#define NBKT 782      // ceil(NN/128)
#define EPB 8192      // edges per block in bucket pass

typedef __attribute__((ext_vector_type(8))) __bf16 bf16x8;
typedef __attribute__((ext_vector_type(4))) float f32x4;

__device__ __forceinline__ float b2f(unsigned short u) {
  union { unsigned int i; float f; } x; x.i = ((unsigned int)u) << 16; return x.f;
}
__device__ __forceinline__ unsigned short f2b(float f) {
  unsigned int i = __float_as_uint(f);
  return (unsigned short)((i + 0x7FFFu + ((i >> 16) & 1u)) >> 16);
}
__device__ __forceinline__ float uf(unsigned int x) { return __uint_as_float(x); }
// custom e4m4 (non-negative): u = ((e32-120)<<4)|m4; decode val = uf(u<<19) * 2^120.
// No denormal bit patterns: codes 1..15 never emitted (flush-to-zero below 2^-6 at encode).
// Exact e4m4 -> bf16: u ? (u<<3)+0x3C00 : 0.
__device__ __forceinline__ unsigned char f2e8(float v) {
  v = fminf(v, 480.f);
  unsigned int ui = __float_as_uint(v);
  ui += 0x3FFFFu + ((ui >> 19) & 1u);  // RNE at 4 mantissa bits
  unsigned int e32 = ui >> 23;
  if (e32 <= 120u) return 0;
  return (unsigned char)(((e32 - 120u) << 4) | ((ui >> 19) & 15u));
}
__device__ __forceinline__ float e82f(unsigned char u) {
  return __uint_as_float(((unsigned int)u) << 19) * 0x1p120f;
}
__device__ __forceinline__ unsigned short e82b(unsigned char u) {
  return u ? (unsigned short)(((unsigned int)u << 3) + 0x3C00u) : (unsigned short)0;
}
// XOR-swizzled LDS address for [row][32] bf16 tiles (row stride 64B).
__device__ __forceinline__ unsigned short* swz(unsigned short* base, int row, int kk) {
  int byte = (row * 64 + kk * 2) ^ ((row & 7) << 4);
  return (unsigned short*)((char*)base + byte);
}
// XOR-swizzled staging address for [row][64] bf16 tiles (row stride 128B); cb = byte in row.
__device__ __forceinline__ char* swzst(unsigned short* base, int row, int cb) {
  int byte = (row * 128 + cb) ^ ((row & 7) << 4);
  return (char*)base + byte;
}

// ---------------- fine-bucketed CSR build (128-col buckets) ----------------
__global__ __launch_bounds__(256) void k_bhist(const int* __restrict__ ecol, int* __restrict__ bcnt) {
  __shared__ int hist[NB2];
  int t = threadIdx.x;
  for (int j = t; j < NB2; j += 256) hist[j] = 0;
  __syncthreads();
  int e0 = blockIdx.x * EPB, e1 = min(e0 + EPB, NE);
  for (int e = e0 + t; e < e1; e += 256) atomicAdd(&hist[ecol[e] >> BSHIFT2], 1);
  __syncthreads();
  for (int j = t; j < NB2; j += 256) if (hist[j]) atomicAdd(&bcnt[j], hist[j]);
}

// exclusive scan of 1024 bucket counts (single 256-thread block, 4 per thread)
__global__ void k_bscan(const int* __restrict__ bcnt, int* __restrict__ bbase, int* __restrict__ cursor) {
  __shared__ int wsum[4];
  int t = threadIdx.x, lane = t & 63, w = t >> 6;
  int4 v = *(const int4*)(bcnt + 4 * t);
  int tot = v.x + v.y + v.z + v.w;
  int s = tot;
  for (int d = 1; d < 64; d <<= 1) { int o = __shfl_up(s, d, 64); if (lane >= d) s += o; }
  if (lane == 63) wsum[w] = s;
  __syncthreads();
  int add = 0;
  for (int i = 0; i < 4; ++i) add += (i < w) ? wsum[i] : 0;
  int excl = add + s - tot;
  int p0 = excl, p1 = p0 + v.x, p2 = p1 + v.y, p3 = p2 + v.z;
  bbase[4 * t] = p0; bbase[4 * t + 1] = p1; bbase[4 * t + 2] = p2; bbase[4 * t + 3] = p3;
  cursor[4 * t] = p0; cursor[4 * t + 1] = p1; cursor[4 * t + 2] = p2; cursor[4 * t + 3] = p3;
}

// place edges into fine-bucketed u32 buffer: (col&127)<<17 | row
__global__ __launch_bounds__(256) void k_bucket(const int* __restrict__ erow, const int* __restrict__ ecol,
                                                int* __restrict__ cursor, unsigned int* __restrict__ ebuf) {
  __shared__ int hist[NB2];
  __shared__ int base[NB2];
  int t = threadIdx.x;
  for (int j = t; j < NB2; j += 256) hist[j] = 0;
  __syncthreads();
  int e0 = blockIdx.x * EPB, e1 = min(e0 + EPB, NE);
  for (int e = e0 + t; e < e1; e += 256) atomicAdd(&hist[ecol[e] >> BSHIFT2], 1);
  __syncthreads();
  for (int j = t; j < NB2; j += 256) {
    int c = hist[j];
    base[j] = (c > 0) ? atomicAdd(&cursor[j], c) : 0;
    hist[j] = 0;  // reuse as local rank cursor
  }
  __syncthreads();
  for (int e = e0 + t; e < e1; e += 256) {
    int col = ecol[e];
    int b = col >> BSHIFT2;
    int r = atomicAdd(&hist[b], 1);
    ebuf[(size_t)base[b] + r] = ((unsigned int)(col & 127) << 17) | (unsigned int)erow[e];
  }
}

// per-bucket col-degree histogram (128 cols) -> deg, dn
__global__ __launch_bounds__(256) void k_subdeg(const unsigned int* __restrict__ ebuf,
                                                const int* __restrict__ bbase, const int* __restrict__ bcnt,
                                                int* __restrict__ deg, float* __restrict__ dn) {
  __shared__ int h[128];
  int t = threadIdx.x, b = blockIdx.x;
  if (t < 128) h[t] = 0;
  __syncthreads();
  int s = bbase[b], e = s + bcnt[b];
  for (int i = s + t; i < e; i += 256) atomicAdd(&h[ebuf[i] >> 17], 1);
  __syncthreads();
  if (t < 128) {
    int col = (b << BSHIFT2) + t;
    if (col < NN) { int d = h[t]; deg[col] = d; dn[col] = d > 0 ? rsqrtf((float)d) : 0.f; }
  }
}

#define SCAN_CH 1024
__global__ void k_scan_part(const int* __restrict__ deg, int* __restrict__ partials) {
  __shared__ int lds[4];
  int b = blockIdx.x, t = threadIdx.x;
  int base = b * SCAN_CH;
  int s = 0;
  for (int j = 0; j < 4; ++j) { int i = base + t + 256 * j; if (i < NN) s += deg[i]; }
  for (int d = 32; d > 0; d >>= 1) s += __shfl_down(s, d, 64);
  int lane = t & 63, w = t >> 6;
  if (lane == 0) lds[w] = s;
  __syncthreads();
  if (t == 0) partials[b] = lds[0] + lds[1] + lds[2] + lds[3];
}

__global__ void k_scan_partials(int* __restrict__ partials, int nb) {
  __shared__ int lds[2];
  int t = threadIdx.x;  // 128 threads, nb <= 128
  int v = (t < nb) ? partials[t] : 0;
  int lane = t & 63, w = t >> 6;
  int s = v;
  for (int d = 1; d < 64; d <<= 1) { int o = __shfl_up(s, d, 64); if (lane >= d) s += o; }
  if (lane == 63) lds[w] = s;
  __syncthreads();
  int base = (w == 1) ? lds[0] : 0;
  if (t < nb) partials[t] = base + s - v;  // exclusive
}

__global__ void k_scan_final(const int* __restrict__ deg, const int* __restrict__ partials,
                             int* __restrict__ colptr, int* __restrict__ pos) {
  __shared__ int lds[4];
  int b = blockIdx.x, t = threadIdx.x;
  int base = b * SCAN_CH + t * 4;
  int d0 = (base + 0 < NN) ? deg[base + 0] : 0;
  int d1 = (base + 1 < NN) ? deg[base + 1] : 0;
  int d2 = (base + 2 < NN) ? deg[base + 2] : 0;
  int d3 = (base + 3 < NN) ? deg[base + 3] : 0;
  int tot = d0 + d1 + d2 + d3;
  int lane = t & 63, w = t >> 6;
  int s = tot;
  for (int d = 1; d < 64; d <<= 1) { int o = __shfl_up(s, d, 64); if (lane >= d) s += o; }
  if (lane == 63) lds[w] = s;
  __syncthreads();
  int wbase = 0;
  for (int i = 0; i < 4; ++i) wbase += (i < w) ? lds[i] : 0;
  int excl = wbase + s - tot + partials[b];
  int p0 = excl, p1 = p0 + d0, p2 = p1 + d1, p3 = p2 + d2, p4 = p3 + d3;
  if (base + 0 <= NN) colptr[base + 0] = p0;
  if (base + 1 <= NN) colptr[base + 1] = p1;
  if (base + 2 <= NN) colptr[base + 2] = p2;
  if (base + 3 <= NN) colptr[base + 3] = p3;
  if (base + 4 == NN) colptr[NN] = p4;
  if (base + 0 < NN) pos[base + 0] = p0;
  if (base + 1 < NN) pos[base + 1] = p1;
  if (base + 2 < NN) pos[base + 2] = p2;
  if (base + 3 < NN) pos[base + 3] = p3;
}

// per-bucket fill: pos atomics hit a 512B window, csr_row writes a ~16KB L2-resident window
__global__ __launch_bounds__(256) void k_fill2(const unsigned int* __restrict__ ebuf,
                                               const int* __restrict__ bbase, const int* __restrict__ bcnt,
                                               int* __restrict__ pos, int* __restrict__ csr_row) {
  int b = blockIdx.x >> 2, sub = blockIdx.x & 3;
  int s = bbase[b], e = s + bcnt[b];
  int cb = b << BSHIFT2;
  for (int i = s + sub * 256 + threadIdx.x; i < e; i += 1024) {
    unsigned int pk = ebuf[i];
    int p = atomicAdd(&pos[cb | (int)(pk >> 17)], 1);
    csr_row[p] = (int)(pk & 0x1FFFF);
  }
}

// ---------------- weight prep (+ zero sentinel row NN of h0s) ----------------
__global__ void k_prep(const float* __restrict__ fc0_W, const float* __restrict__ fc0_b,
                       const float* __restrict__ conv_W, const float* __restrict__ conv_b,
                       const float* __restrict__ bn_gamma, const float* __restrict__ bn_beta,
                       const float* __restrict__ bn_mean, const float* __restrict__ bn_var,
                       const float* __restrict__ clf_W,
                       unsigned short* __restrict__ W0t, unsigned short* __restrict__ Wct,
                       unsigned short* __restrict__ Wclft,
                       float* __restrict__ epia, float* __restrict__ epib,
                       unsigned char* __restrict__ h0s) {
  int idx = blockIdx.x * 256 + threadIdx.x;
  if (idx < 131072) {                       // W0t[n*512+k] = fc0_W[k][n]
    int n = idx >> 9, k = idx & 511;
    W0t[idx] = f2b(fc0_W[k * 256 + n]);
  } else if (idx < 262144) {                // Wct[l][n*256+k] = conv_W[l][k][n]
    int j = idx - 131072;
    int l = j >> 16, rem = j & 65535, n = rem >> 8, k = rem & 255;
    Wct[j] = f2b(conv_W[l * 65536 + k * 256 + n]);
  } else if (idx < 262144 + 48 * 256) {     // Wclft[n*256+k], rows 40..47 zero
    int j = idx - 262144;
    int n = j >> 8, k = j & 255;
    Wclft[j] = f2b(n < NOUT ? clf_W[k * NOUT + n] : 0.f);
  } else if (idx < 262144 + 12288 + 768) {  // epilogue constants per BN layer
    int j = idx - 262144 - 12288;           // layer*256 + c
    int layer = j >> 8, c = j & 255;
    float a = bn_gamma[j] * rsqrtf(bn_var[j] + 1e-5f);
    float bias = (layer == 0) ? fc0_b[c] : conv_b[(layer - 1) * 256 + c];
    epia[j] = a;
    epib[j] = bn_beta[j] + (bias - bn_mean[j]) * a;
  } else if (idx < 262144 + 12288 + 768 + 256) {  // zero gather-sink row NN (e4m4)
    int c = idx - (262144 + 12288 + 768);
    h0s[(size_t)NN * HID + c] = 0;
  }
}

// ---------------- MFMA GEMM, 128x256 tile, 8 waves (4x2), pipelined K-loop ----------------
// ALAY: 0 = f32 A, 1 = bf16 A, 2 = e4m4 A.
// EPI 0 (fc0):    stage y=relu(a*acc+b); store h0s=e4m4(dn*y); fused clf partial outv=y@Wclft (f32)
// EPI 1 (conv0):  stage y*dn; store outv=e4m4(y*dn + decode(prev e4m4)) (in-place h0s->h1s)
// EPI 4 (conv1):  stage y; no tile store; fused clf: outv = y@Wclft + prevv(outP) + clfb (f32)
// Epilogue: 4 chunks of 64 cols staged via ldsB (bf16, swizzled); fused clf MFMAs read the stage.
template <int K, int ALAY, int EPI>
__global__ __launch_bounds__(512) void k_gemm2(const void* __restrict__ Av,
                                               const unsigned short* __restrict__ Bt,
                                               const float* __restrict__ epia,
                                               const float* __restrict__ epib,
                                               const void* prevv,
                                               const float* __restrict__ dnp,
                                               const unsigned short* __restrict__ clfW,
                                               const float* __restrict__ clfb,
                                               void* outv, void* outv2) {
  __shared__ unsigned short ldsA[128 * 32];  // 8KB
  __shared__ unsigned short ldsB[256 * 32];  // 16KB; reused as 128x64 bf16 stage in epilogue
  constexpr bool DOCLF = (EPI == 0 || EPI == 4);
  const int t = threadIdx.x;
  const int w = t >> 6, lane = t & 63;
  const int lo = lane & 15, hi = lane >> 4;
  const int wr = w >> 1, wc = w & 1;
  const int m0 = blockIdx.x * 128;
  constexpr int NK = K / 32;
  f32x4 acc[2][8];
#pragma unroll
  for (int m = 0; m < 2; ++m)
#pragma unroll
    for (int f = 0; f < 8; ++f) acc[m][f] = (f32x4){0.f, 0.f, 0.f, 0.f};
  f32x4 accclf[3];
#pragma unroll
  for (int f = 0; f < 3; ++f) accclf[f] = (f32x4){0.f, 0.f, 0.f, 0.f};

  const int arow = t >> 2;       // 0..127
  const int akk = (t & 3) * 8;   // element offset in K-step
  const int rg = m0 + arow;
  const int bn0 = t >> 2, bn1 = bn0 + 128;

  // register stage
  float4 rv0, rv1;
  int4 ra;
  uint2 rae;

#define LOADG(k0_) {                                                        \
    if (ALAY == 0) {                                                        \
      const float* A = (const float*)Av;                                    \
      rv0 = (float4){0.f, 0.f, 0.f, 0.f}; rv1 = rv0;                        \
      if (rg < NN) {                                                        \
        rv0 = *(const float4*)(A + (size_t)rg * K + (k0_) + akk);           \
        rv1 = *(const float4*)(A + (size_t)rg * K + (k0_) + akk + 4);       \
      }                                                                     \
    } else if (ALAY == 1) {                                                 \
      const unsigned short* A = (const unsigned short*)Av;                  \
      ra = (int4){0, 0, 0, 0};                                              \
      if (rg < NN) ra = *(const int4*)(A + (size_t)rg * K + (k0_) + akk);   \
    } else {                                                                \
      const unsigned char* A = (const unsigned char*)Av;                    \
      rae = (uint2){0u, 0u};                                                \
      if (rg < NN) rae = *(const uint2*)(A + (size_t)rg * K + (k0_) + akk); \
    }                                                                       \
    rb0 = *(const int4*)(Bt + (size_t)bn0 * K + (k0_) + akk);               \
    rb1 = *(const int4*)(Bt + (size_t)bn1 * K + (k0_) + akk);               \
  }
#define WRITELDS() {                                                        \
    if (ALAY == 0) {                                                        \
      union { unsigned short u[8]; int4 v; } pk;                            \
      pk.u[0] = f2b(rv0.x); pk.u[1] = f2b(rv0.y);                           \
      pk.u[2] = f2b(rv0.z); pk.u[3] = f2b(rv0.w);                           \
      pk.u[4] = f2b(rv1.x); pk.u[5] = f2b(rv1.y);                           \
      pk.u[6] = f2b(rv1.z); pk.u[7] = f2b(rv1.w);                           \
      *(int4*)(void*)swz(ldsA, arow, akk) = pk.v;                           \
    } else if (ALAY == 1) {                                                 \
      *(int4*)(void*)swz(ldsA, arow, akk) = ra;                             \
    } else {                                                                \
      union { unsigned char b[8]; uint2 v2; } in; in.v2 = rae;              \
      union { unsigned short u[8]; int4 v; } pk;                            \
      _Pragma("unroll") for (int q = 0; q < 8; ++q) pk.u[q] = e82b(in.b[q]);\
      *(int4*)(void*)swz(ldsA, arow, akk) = pk.v;                           \
    }                                                                       \
    *(int4*)(void*)swz(ldsB, bn0, akk) = rb0;                               \
    *(int4*)(void*)swz(ldsB, bn1, akk) = rb1;                               \
  }

  int4 rb0, rb1;
  LOADG(0);
  for (int k = 0; k < NK; ++k) {
    // barrier A: all waves done reading LDS (lgkm only -- in-flight gloads survive)
    asm volatile("s_waitcnt lgkmcnt(0)" ::: "memory");
    __builtin_amdgcn_s_barrier();
    __builtin_amdgcn_sched_barrier(0);
    WRITELDS();
    __syncthreads();
    if (k + 1 < NK) LOADG((k + 1) * 32);
    bf16x8 af0 = *(const bf16x8*)(void*)swz(ldsA, wr * 32 + lo, hi * 8);
    bf16x8 af1 = *(const bf16x8*)(void*)swz(ldsA, wr * 32 + 16 + lo, hi * 8);
#pragma unroll
    for (int f = 0; f < 8; ++f) {
      bf16x8 bf = *(const bf16x8*)(void*)swz(ldsB, wc * 128 + f * 16 + lo, hi * 8);
      acc[0][f] = __builtin_amdgcn_mfma_f32_16x16x32_bf16(af0, bf, acc[0][f], 0, 0, 0);
      acc[1][f] = __builtin_amdgcn_mfma_f32_16x16x32_bf16(af1, bf, acc[1][f], 0, 0, 0);
    }
  }
  // final barrier before epilogue stage reuse of ldsB
  asm volatile("s_waitcnt lgkmcnt(0)" ::: "memory");
  __builtin_amdgcn_s_barrier();
  __builtin_amdgcn_sched_barrier(0);

  // ---- staged epilogue: 4 chunks of 64 columns ----
#pragma unroll
  for (int cc = 0; cc < 4; ++cc) {
    if (cc) __syncthreads();  // protect stage reuse
    if (wc == (cc >> 1)) {
#pragma unroll
      for (int m = 0; m < 2; ++m) {
        const int rb = wr * 32 + m * 16 + hi * 4;
#pragma unroll
        for (int fl = 0; fl < 4; ++fl) {
          const int f = (cc & 1) * 4 + fl;
          const int c = wc * 128 + f * 16 + lo;  // global column
          float a_ = epia[c], b_ = epib[c];
#pragma unroll
          for (int j = 0; j < 4; ++j) {
            int row = rb + j;
            int r = m0 + row;
            float y = fmaxf(a_ * acc[m][f][j] + b_, 0.f);
            float sv;
            if constexpr (EPI == 1) {
              float dnv = (r < NN) ? dnp[r] : 0.f;
              sv = y * dnv;
            } else {
              sv = y;
            }
            *(unsigned short*)swzst(ldsB, row, (fl * 16 + lo) * 2) = f2b(sv);
          }
        }
      }
    }
    __syncthreads();
    // coalesced store phase (EPI 0: e4m4 scaled; EPI 1: e4m4 + prev; EPI 4: none)
    if constexpr (EPI == 0 || EPI == 1) {
#pragma unroll
      for (int pass = 0; pass < 2; ++pass) {
        int rr = pass * 64 + (t >> 3);
        int r = m0 + rr;
        int cb = (t & 7) * 16;
        uint4 v = *(const uint4*)swzst(ldsB, rr, cb);
        if (r < NN) {
          size_t gix = (size_t)r * HID + cc * 64 + (t & 7) * 8;
          union { unsigned short u[8]; uint4 v4; } sb; sb.v4 = v;
          if constexpr (EPI == 0) {
            float d = dnp[r];
            union { unsigned char b[8]; uint2 v2; } o8;
#pragma unroll
            for (int q = 0; q < 8; ++q) o8.b[q] = f2e8(d * b2f(sb.u[q]));
            *(uint2*)((unsigned char*)outv2 + gix) = o8.v2;
          } else {
            union { unsigned char b[8]; uint2 v2; } pv;
            pv.v2 = *(const uint2*)((const unsigned char*)prevv + gix);
            union { unsigned char b[8]; uint2 v2; } o8;
#pragma unroll
            for (int q = 0; q < 8; ++q) o8.b[q] = f2e8(b2f(sb.u[q]) + e82f(pv.b[q]));
            *(uint2*)((unsigned char*)outv + gix) = o8.v2;
          }
        }
      }
    }
    // fused classifier MFMAs on the staged chunk (K-slice = cols cc*64..cc*64+63)
    if constexpr (DOCLF) {
#pragma unroll
      for (int kk = 0; kk < 2; ++kk) {
        bf16x8 af = *(const bf16x8*)(const void*)swzst(ldsB, w * 16 + lo, (kk * 32 + hi * 8) * 2);
#pragma unroll
        for (int f = 0; f < 3; ++f) {
          bf16x8 bf = *(const bf16x8*)(clfW + (size_t)(f * 16 + lo) * HID + cc * 64 + kk * 32 + hi * 8);
          accclf[f] = __builtin_amdgcn_mfma_f32_16x16x32_bf16(af, bf, accclf[f], 0, 0, 0);
        }
      }
    }
  }
  if constexpr (DOCLF) {
    // clf write: wave w owns rows m0+w*16.., C/D layout col=lo, row=hi*4+j
#pragma unroll
    for (int f = 0; f < 3; ++f) {
      int c = f * 16 + lo;
      if (c < NOUT) {
#pragma unroll
        for (int j = 0; j < 4; ++j) {
          int r = m0 + w * 16 + hi * 4 + j;
          if (r < NN) {
            if constexpr (EPI == 0) {
              ((float*)outv)[(size_t)r * NOUT + c] = accclf[f][j];
            } else {
              ((float*)outv)[(size_t)r * NOUT + c] =
                  accclf[f][j] + ((const float*)prevv)[(size_t)r * NOUT + c] + clfb[c];
            }
          }
        }
      }
    }
  }
#undef LOADG
#undef WRITELDS
}

// ---------------- aggregation: 3-stage pipelined paired-edge e4m4 gather ----------------
// wave = 1 node. Lanes 0-31: even edges, 32-63: odd edges; 8B = 8 feats/lane (256B/row).
// Decode: raw += uf((byte<<19)&0x07F80000); final scale by dn[i]*2^120. Output e4m4.
__global__ __launch_bounds__(256) void k_agg(const int* __restrict__ colptr,
                                             const int* __restrict__ csr,
                                             const float* __restrict__ dn,
                                             const unsigned char* __restrict__ hs,
                                             unsigned char* __restrict__ X) {
  int w = threadIdx.x >> 6, lane = threadIdx.x & 63;
  int i = blockIdx.x * 4 + w;
  int hl = lane & 31, half = lane >> 5;
  const unsigned char* hb = hs + hl * 8;
  int e0 = colptr[i], e1 = colptr[i + 1];
  float a0 = 0, a1 = 0, a2 = 0, a3 = 0, a4 = 0, a5 = 0, a6 = 0, a7 = 0;
  int rA[4], rB[4];
  uint2 vA[4], vB[4];

#define LOADIDX(e_, r_) { \
  _Pragma("unroll") for (int u = 0; u < 4; ++u) { \
    int ee = (e_) + 2 * u + half; \
    int rr = csr[ee]; \
    r_[u] = (ee < e1) ? rr : NN; } }
#define GATHER(r_, v_) { \
  _Pragma("unroll") for (int u = 0; u < 4; ++u) \
    v_[u] = *(const uint2*)(hb + (size_t)r_[u] * HID); }
#define ACCUM(v_) { \
  _Pragma("unroll") for (int u = 0; u < 4; ++u) { \
    a0 += uf((v_[u].x << 19) & 0x07F80000u); a1 += uf((v_[u].x << 11) & 0x07F80000u); \
    a2 += uf((v_[u].x << 3)  & 0x07F80000u); a3 += uf((v_[u].x >> 5)  & 0x07F80000u); \
    a4 += uf((v_[u].y << 19) & 0x07F80000u); a5 += uf((v_[u].y << 11) & 0x07F80000u); \
    a6 += uf((v_[u].y << 3)  & 0x07F80000u); a7 += uf((v_[u].y >> 5)  & 0x07F80000u); } }

  int nb = (e1 - e0 + 7) >> 3;
  if (nb == 1) {
    LOADIDX(e0, rA); GATHER(rA, vA); ACCUM(vA);
  } else if (nb > 1) {
    LOADIDX(e0, rA);
    GATHER(rA, vA);
    LOADIDX(e0 + 8, rB);
    int b = 1, e = e0 + 8;
    for (; b + 1 < nb; ++b, e += 8) {
      if (b & 1) { GATHER(rB, vB); LOADIDX(e + 8, rA); ACCUM(vA); }
      else       { GATHER(rA, vA); LOADIDX(e + 8, rB); ACCUM(vB); }
    }
    if (b & 1) { GATHER(rB, vB); ACCUM(vA); ACCUM(vB); }
    else       { GATHER(rA, vA); ACCUM(vB); ACCUM(vA); }
  }
  // merge even/odd halves (lane ^ 32 holds same features)
  a0 += __shfl_xor(a0, 32); a1 += __shfl_xor(a1, 32);
  a2 += __shfl_xor(a2, 32); a3 += __shfl_xor(a3, 32);
  a4 += __shfl_xor(a4, 32); a5 += __shfl_xor(a5, 32);
  a6 += __shfl_xor(a6, 32); a7 += __shfl_xor(a7, 32);
  if (half == 0) {
    float d = dn[i] * 0x1p120f;  // fold e4m4 rescale into dn
    union { unsigned char b[8]; uint2 v; } o;
    o.b[0] = f2e8(d * a0); o.b[1] = f2e8(d * a1); o.b[2] = f2e8(d * a2); o.b[3] = f2e8(d * a3);
    o.b[4] = f2e8(d * a4); o.b[5] = f2e8(d * a5); o.b[6] = f2e8(d * a6); o.b[7] = f2e8(d * a7);
    *(uint2*)(X + (size_t)i * HID + hl * 8) = o.v;
  }
}

extern "C" void kernel_launch(void* const* d_in, const int* in_sizes, int n_in,
                              void* d_out, int out_size, void* d_ws, size_t ws_size,
                              hipStream_t stream) {
  const float* x        = (const float*)d_in[0];
  const int*   edge     = (const int*)d_in[1];
  const int*   erow     = edge;
  const int*   ecol     = edge + NE;
  const float* fc0_W    = (const float*)d_in[2];
  const float* fc0_b    = (const float*)d_in[3];
  const float* conv_W   = (const float*)d_in[4];
  const float* conv_b   = (const float*)d_in[5];
  const float* bn_gamma = (const float*)d_in[6];
  const float* bn_beta  = (const float*)d_in[7];
  const float* bn_mean  = (const float*)d_in[8];
  const float* bn_var   = (const float*)d_in[9];
  const float* clf_W    = (const float*)d_in[10];
  const float* clf_b    = (const float*)d_in[11];

  char* p = (char*)d_ws;
  auto alloc = [&](size_t bytes) { char* r = p; p += (bytes + 255) & ~(size_t)255; return r; };
  int*   deg      = (int*)alloc((size_t)NN * 4);
  float* dn       = (float*)alloc((size_t)NN * 4);
  int*   colptr   = (int*)alloc((size_t)(NN + 1) * 4);
  int*   pos      = (int*)alloc((size_t)NN * 4);
  int*   partials = (int*)alloc(1024);
  int*   bcnt     = (int*)alloc(NB2 * 4);
  int*   bbase    = (int*)alloc(NB2 * 4);
  int*   cursor   = (int*)alloc(NB2 * 4);
  int*   csr_row  = (int*)alloc(((size_t)NE + 16) * 4);
  unsigned short* W0t   = (unsigned short*)alloc((size_t)256 * 512 * 2);
  unsigned short* Wct   = (unsigned short*)alloc((size_t)2 * 256 * 256 * 2);
  unsigned short* Wclft = (unsigned short*)alloc((size_t)48 * 256 * 2);
  float* epia = (float*)alloc(768 * 4);
  float* epib = (float*)alloc(768 * 4);
  float* outP = (float*)alloc((size_t)NN * NOUT * 4);                      // clf partial h0@W
  unsigned char*  h0s = (unsigned char*)alloc((size_t)(NN + 1) * HID);     // e4m4 (+zero row NN); becomes h1s
  unsigned char*  X   = (unsigned char*)alloc((size_t)NN * HID);           // agg output (e4m4)
  unsigned int* ebuf = (unsigned int*)X;  // alias: ebuf (12.8MB) dead before X (25.6MB) first written

  int nbBlk = (NE + EPB - 1) / EPB;  // 391
  hipMemsetAsync(bcnt, 0, NB2 * 4, stream);
  k_bhist<<<nbBlk, 256, 0, stream>>>(ecol, bcnt);
  k_bscan<<<1, 256, 0, stream>>>(bcnt, bbase, cursor);
  k_bucket<<<nbBlk, 256, 0, stream>>>(erow, ecol, cursor, ebuf);
  k_subdeg<<<NBKT, 256, 0, stream>>>(ebuf, bbase, bcnt, deg, dn);
  int nb = (NN + SCAN_CH - 1) / SCAN_CH;  // 98
  k_scan_part<<<nb, 256, 0, stream>>>(deg, partials);
  k_scan_partials<<<1, 128, 0, stream>>>(partials, nb);
  k_scan_final<<<nb, 256, 0, stream>>>(deg, partials, colptr, pos);
  k_fill2<<<NBKT * 4, 256, 0, stream>>>(ebuf, bbase, bcnt, pos, csr_row);
  k_prep<<<1076, 256, 0, stream>>>(fc0_W, fc0_b, conv_W, conv_b, bn_gamma, bn_beta,
                                   bn_mean, bn_var, clf_W, W0t, Wct, Wclft, epia, epib, h0s);

  int gm2 = (NN + 127) / 128;  // 782
  // fc0 + BN0 + ReLU -> h0s (e4m4, dn-scaled) + outP = h0@Wclft (f32)
  k_gemm2<KIN, 0, 0><<<gm2, 512, 0, stream>>>(x, W0t, epia, epib, nullptr, dn, Wclft, nullptr, outP, h0s);
  // layer 0: agg(h0s) -> X (e4m4); gemm: scaled residual, in-place h0s -> h1s (e4m4)
  k_agg<<<(NN + 3) / 4, 256, 0, stream>>>(colptr, csr_row, dn, h0s, X);
  k_gemm2<HID, 2, 1><<<gm2, 512, 0, stream>>>(X, Wct, epia + 256, epib + 256, h0s, dn, nullptr, nullptr, h0s, nullptr);
  // layer 1: agg(h1s) -> X (e4m4); gemm: fused clf -> out = y@Wclft + outP + clf_b
  k_agg<<<(NN + 3) / 4, 256, 0, stream>>>(colptr, csr_row, dn, h0s, X);
  k_gemm2<HID, 2, 4><<<gm2, 512, 0, stream>>>(X, Wct + 65536, epia + 512, epib + 512, outP, nullptr, Wclft, clf_b, d_out, nullptr);
}

// Round 18
// 591.402 us; speedup vs baseline: 1.2774x; 1.0506x over previous
//
#include <hip/hip_runtime.h>
#include <stdint.h>

#define NN 100000
#define NE 3200000
#define KIN 512
#define HID 256
#define NOUT 40
#define NB2 1024      // fine col-buckets (col >> 7); 782 used
#define BSHIFT2 7
#define NBKT 782      // ceil(NN/128)
#define EPB 8192      // edges per block in bucket pass

typedef __attribute__((ext_vector_type(8))) __bf16 bf16x8;
typedef __attribute__((ext_vector_type(4))) float f32x4;

__device__ __forceinline__ float b2f(unsigned short u) {
  union { unsigned int i; float f; } x; x.i = ((unsigned int)u) << 16; return x.f;
}
__device__ __forceinline__ unsigned short f2b(float f) {
  unsigned int i = __float_as_uint(f);
  return (unsigned short)((i + 0x7FFFu + ((i >> 16) & 1u)) >> 16);
}
__device__ __forceinline__ float uf(unsigned int x) { return __uint_as_float(x); }
// custom e4m4 (non-negative): u = ((e32-120)<<4)|m4; decode val = uf(u<<19) * 2^120.
// No denormal bit patterns: codes 1..15 never emitted (flush-to-zero below 2^-6 at encode).
// Exact e4m4 -> bf16: u ? (u<<3)+0x3C00 : 0.
__device__ __forceinline__ unsigned char f2e8(float v) {
  v = fminf(v, 480.f);
  unsigned int ui = __float_as_uint(v);
  ui += 0x3FFFFu + ((ui >> 19) & 1u);  // RNE at 4 mantissa bits
  unsigned int e32 = ui >> 23;
  if (e32 <= 120u) return 0;
  return (unsigned char)(((e32 - 120u) << 4) | ((ui >> 19) & 15u));
}
__device__ __forceinline__ float e82f(unsigned char u) {
  return __uint_as_float(((unsigned int)u) << 19) * 0x1p120f;
}
__device__ __forceinline__ unsigned short e82b(unsigned char u) {
  return u ? (unsigned short)(((unsigned int)u << 3) + 0x3C00u) : (unsigned short)0;
}
// XOR-swizzled LDS address for [row][32] bf16 tiles (row stride 64B).
__device__ __forceinline__ unsigned short* swz(unsigned short* base, int row, int kk) {
  int byte = (row * 64 + kk * 2) ^ ((row & 7) << 4);
  return (unsigned short*)((char*)base + byte);
}
// XOR-swizzled staging address for [row][64] bf16 tiles (row stride 128B); cb = byte in row.
__device__ __forceinline__ char* swzst(unsigned short* base, int row, int cb) {
  int byte = (row * 128 + cb) ^ ((row & 7) << 4);
  return (char*)base + byte;
}

// ---------------- fine-bucketed CSR build (128-col buckets) ----------------
__global__ __launch_bounds__(256) void k_bhist(const int* __restrict__ ecol, int* __restrict__ bcnt) {
  __shared__ int hist[NB2];
  int t = threadIdx.x;
  for (int j = t; j < NB2; j += 256) hist[j] = 0;
  __syncthreads();
  int e0 = blockIdx.x * EPB, e1 = min(e0 + EPB, NE);
  for (int e = e0 + t; e < e1; e += 256) atomicAdd(&hist[ecol[e] >> BSHIFT2], 1);
  __syncthreads();
  for (int j = t; j < NB2; j += 256) if (hist[j]) atomicAdd(&bcnt[j], hist[j]);
}

// exclusive scan of 1024 bucket counts (single 256-thread block, 4 per thread)
__global__ void k_bscan(const int* __restrict__ bcnt, int* __restrict__ bbase, int* __restrict__ cursor) {
  __shared__ int wsum[4];
  int t = threadIdx.x, lane = t & 63, w = t >> 6;
  int4 v = *(const int4*)(bcnt + 4 * t);
  int tot = v.x + v.y + v.z + v.w;
  int s = tot;
  for (int d = 1; d < 64; d <<= 1) { int o = __shfl_up(s, d, 64); if (lane >= d) s += o; }
  if (lane == 63) wsum[w] = s;
  __syncthreads();
  int add = 0;
  for (int i = 0; i < 4; ++i) add += (i < w) ? wsum[i] : 0;
  int excl = add + s - tot;
  int p0 = excl, p1 = p0 + v.x, p2 = p1 + v.y, p3 = p2 + v.z;
  bbase[4 * t] = p0; bbase[4 * t + 1] = p1; bbase[4 * t + 2] = p2; bbase[4 * t + 3] = p3;
  cursor[4 * t] = p0; cursor[4 * t + 1] = p1; cursor[4 * t + 2] = p2; cursor[4 * t + 3] = p3;
}

// place edges into fine-bucketed u32 buffer: (col&127)<<17 | row
__global__ __launch_bounds__(256) void k_bucket(const int* __restrict__ erow, const int* __restrict__ ecol,
                                                int* __restrict__ cursor, unsigned int* __restrict__ ebuf) {
  __shared__ int hist[NB2];
  __shared__ int base[NB2];
  int t = threadIdx.x;
  for (int j = t; j < NB2; j += 256) hist[j] = 0;
  __syncthreads();
  int e0 = blockIdx.x * EPB, e1 = min(e0 + EPB, NE);
  for (int e = e0 + t; e < e1; e += 256) atomicAdd(&hist[ecol[e] >> BSHIFT2], 1);
  __syncthreads();
  for (int j = t; j < NB2; j += 256) {
    int c = hist[j];
    base[j] = (c > 0) ? atomicAdd(&cursor[j], c) : 0;
    hist[j] = 0;  // reuse as local rank cursor
  }
  __syncthreads();
  for (int e = e0 + t; e < e1; e += 256) {
    int col = ecol[e];
    int b = col >> BSHIFT2;
    int r = atomicAdd(&hist[b], 1);
    ebuf[(size_t)base[b] + r] = ((unsigned int)(col & 127) << 17) | (unsigned int)erow[e];
  }
}

// per-bucket col-degree histogram (128 cols) -> deg, dn
__global__ __launch_bounds__(256) void k_subdeg(const unsigned int* __restrict__ ebuf,
                                                const int* __restrict__ bbase, const int* __restrict__ bcnt,
                                                int* __restrict__ deg, float* __restrict__ dn) {
  __shared__ int h[128];
  int t = threadIdx.x, b = blockIdx.x;
  if (t < 128) h[t] = 0;
  __syncthreads();
  int s = bbase[b], e = s + bcnt[b];
  for (int i = s + t; i < e; i += 256) atomicAdd(&h[ebuf[i] >> 17], 1);
  __syncthreads();
  if (t < 128) {
    int col = (b << BSHIFT2) + t;
    if (col < NN) { int d = h[t]; deg[col] = d; dn[col] = d > 0 ? rsqrtf((float)d) : 0.f; }
  }
}

#define SCAN_CH 1024
__global__ void k_scan_part(const int* __restrict__ deg, int* __restrict__ partials) {
  __shared__ int lds[4];
  int b = blockIdx.x, t = threadIdx.x;
  int base = b * SCAN_CH;
  int s = 0;
  for (int j = 0; j < 4; ++j) { int i = base + t + 256 * j; if (i < NN) s += deg[i]; }
  for (int d = 32; d > 0; d >>= 1) s += __shfl_down(s, d, 64);
  int lane = t & 63, w = t >> 6;
  if (lane == 0) lds[w] = s;
  __syncthreads();
  if (t == 0) partials[b] = lds[0] + lds[1] + lds[2] + lds[3];
}

__global__ void k_scan_partials(int* __restrict__ partials, int nb) {
  __shared__ int lds[2];
  int t = threadIdx.x;  // 128 threads, nb <= 128
  int v = (t < nb) ? partials[t] : 0;
  int lane = t & 63, w = t >> 6;
  int s = v;
  for (int d = 1; d < 64; d <<= 1) { int o = __shfl_up(s, d, 64); if (lane >= d) s += o; }
  if (lane == 63) lds[w] = s;
  __syncthreads();
  int base = (w == 1) ? lds[0] : 0;
  if (t < nb) partials[t] = base + s - v;  // exclusive
}

__global__ void k_scan_final(const int* __restrict__ deg, const int* __restrict__ partials,
                             int* __restrict__ colptr, int* __restrict__ pos) {
  __shared__ int lds[4];
  int b = blockIdx.x, t = threadIdx.x;
  int base = b * SCAN_CH + t * 4;
  int d0 = (base + 0 < NN) ? deg[base + 0] : 0;
  int d1 = (base + 1 < NN) ? deg[base + 1] : 0;
  int d2 = (base + 2 < NN) ? deg[base + 2] : 0;
  int d3 = (base + 3 < NN) ? deg[base + 3] : 0;
  int tot = d0 + d1 + d2 + d3;
  int lane = t & 63, w = t >> 6;
  int s = tot;
  for (int d = 1; d < 64; d <<= 1) { int o = __shfl_up(s, d, 64); if (lane >= d) s += o; }
  if (lane == 63) lds[w] = s;
  __syncthreads();
  int wbase = 0;
  for (int i = 0; i < 4; ++i) wbase += (i < w) ? lds[i] : 0;
  int excl = wbase + s - tot + partials[b];
  int p0 = excl, p1 = p0 + d0, p2 = p1 + d1, p3 = p2 + d2, p4 = p3 + d3;
  if (base + 0 <= NN) colptr[base + 0] = p0;
  if (base + 1 <= NN) colptr[base + 1] = p1;
  if (base + 2 <= NN) colptr[base + 2] = p2;
  if (base + 3 <= NN) colptr[base + 3] = p3;
  if (base + 4 == NN) colptr[NN] = p4;
  if (base + 0 < NN) pos[base + 0] = p0;
  if (base + 1 < NN) pos[base + 1] = p1;
  if (base + 2 < NN) pos[base + 2] = p2;
  if (base + 3 < NN) pos[base + 3] = p3;
}

// per-bucket fill: pos atomics hit a 512B window, csr_row writes a ~16KB L2-resident window
__global__ __launch_bounds__(256) void k_fill2(const unsigned int* __restrict__ ebuf,
                                               const int* __restrict__ bbase, const int* __restrict__ bcnt,
                                               int* __restrict__ pos, int* __restrict__ csr_row) {
  int b = blockIdx.x >> 2, sub = blockIdx.x & 3;
  int s = bbase[b], e = s + bcnt[b];
  int cb = b << BSHIFT2;
  for (int i = s + sub * 256 + threadIdx.x; i < e; i += 1024) {
    unsigned int pk = ebuf[i];
    int p = atomicAdd(&pos[cb | (int)(pk >> 17)], 1);
    csr_row[p] = (int)(pk & 0x1FFFF);
  }
}

// ---------------- weight prep (+ zero sentinel row NN of h0s) ----------------
__global__ void k_prep(const float* __restrict__ fc0_W, const float* __restrict__ fc0_b,
                       const float* __restrict__ conv_W, const float* __restrict__ conv_b,
                       const float* __restrict__ bn_gamma, const float* __restrict__ bn_beta,
                       const float* __restrict__ bn_mean, const float* __restrict__ bn_var,
                       const float* __restrict__ clf_W,
                       unsigned short* __restrict__ W0t, unsigned short* __restrict__ Wct,
                       unsigned short* __restrict__ Wclft,
                       float* __restrict__ epia, float* __restrict__ epib,
                       unsigned char* __restrict__ h0s) {
  int idx = blockIdx.x * 256 + threadIdx.x;
  if (idx < 131072) {                       // W0t[n*512+k] = fc0_W[k][n]
    int n = idx >> 9, k = idx & 511;
    W0t[idx] = f2b(fc0_W[k * 256 + n]);
  } else if (idx < 262144) {                // Wct[l][n*256+k] = conv_W[l][k][n]
    int j = idx - 131072;
    int l = j >> 16, rem = j & 65535, n = rem >> 8, k = rem & 255;
    Wct[j] = f2b(conv_W[l * 65536 + k * 256 + n]);
  } else if (idx < 262144 + 48 * 256) {     // Wclft[n*256+k], rows 40..47 zero
    int j = idx - 262144;
    int n = j >> 8, k = j & 255;
    Wclft[j] = f2b(n < NOUT ? clf_W[k * NOUT + n] : 0.f);
  } else if (idx < 262144 + 12288 + 768) {  // epilogue constants per BN layer
    int j = idx - 262144 - 12288;           // layer*256 + c
    int layer = j >> 8, c = j & 255;
    float a = bn_gamma[j] * rsqrtf(bn_var[j] + 1e-5f);
    float bias = (layer == 0) ? fc0_b[c] : conv_b[(layer - 1) * 256 + c];
    epia[j] = a;
    epib[j] = bn_beta[j] + (bias - bn_mean[j]) * a;
  } else if (idx < 262144 + 12288 + 768 + 256) {  // zero gather-sink row NN (e4m4)
    int c = idx - (262144 + 12288 + 768);
    h0s[(size_t)NN * HID + c] = 0;
  }
}

// ---------------- MFMA GEMM, 128x256 tile, 8 waves (4x2), pipelined K-loop (UNFUSED) ------
// Total regs/wave ~128 (64 acc + ~64 arch) -> 2 blocks/CU resident (the occupancy lever).
// ALAY: 0 = f32 A, 2 = e4m4 A.
// EPI 0 (fc0):   stage y; store out=h0 (bf16) + out2=e4m4(dn*y)
// EPI 1 (conv0): stage y*dn; store out=e4m4(y*dn + decode(prev e4m4)) (in-place h0s->h1s)
// EPI 3 (conv1): stage y; store out=bf16(y + prev bf16) (in-place h0 -> h2)
// Epilogue: 4 chunks of 64 cols staged via ldsB (bf16, swizzled) -> coalesced stores.
template <int K, int ALAY, int EPI>
__global__ __launch_bounds__(512) void k_gemm2(const void* __restrict__ Av,
                                               const unsigned short* __restrict__ Bt,
                                               const float* __restrict__ epia,
                                               const float* __restrict__ epib,
                                               const void* prevv,
                                               const float* __restrict__ dnp,
                                               void* outv, void* outv2) {
  __shared__ unsigned short ldsA[128 * 32];  // 8KB
  __shared__ unsigned short ldsB[256 * 32];  // 16KB; reused as 128x64 bf16 stage in epilogue
  const int t = threadIdx.x;
  const int w = t >> 6, lane = t & 63;
  const int lo = lane & 15, hi = lane >> 4;
  const int wr = w >> 1, wc = w & 1;
  const int m0 = blockIdx.x * 128;
  constexpr int NK = K / 32;
  f32x4 acc[2][8];
#pragma unroll
  for (int m = 0; m < 2; ++m)
#pragma unroll
    for (int f = 0; f < 8; ++f) acc[m][f] = (f32x4){0.f, 0.f, 0.f, 0.f};

  const int arow = t >> 2;       // 0..127
  const int akk = (t & 3) * 8;   // element offset in K-step
  const int rg = m0 + arow;
  const int bn0 = t >> 2, bn1 = bn0 + 128;

  // register stage
  float4 rv0, rv1;
  uint2 rae;
  int4 rb0, rb1;

#define LOADG(k0_) {                                                        \
    if (ALAY == 0) {                                                        \
      const float* A = (const float*)Av;                                    \
      rv0 = (float4){0.f, 0.f, 0.f, 0.f}; rv1 = rv0;                        \
      if (rg < NN) {                                                        \
        rv0 = *(const float4*)(A + (size_t)rg * K + (k0_) + akk);           \
        rv1 = *(const float4*)(A + (size_t)rg * K + (k0_) + akk + 4);       \
      }                                                                     \
    } else {                                                                \
      const unsigned char* A = (const unsigned char*)Av;                    \
      rae = (uint2){0u, 0u};                                                \
      if (rg < NN) rae = *(const uint2*)(A + (size_t)rg * K + (k0_) + akk); \
    }                                                                       \
    rb0 = *(const int4*)(Bt + (size_t)bn0 * K + (k0_) + akk);               \
    rb1 = *(const int4*)(Bt + (size_t)bn1 * K + (k0_) + akk);               \
  }
#define WRITELDS() {                                                        \
    if (ALAY == 0) {                                                        \
      union { unsigned short u[8]; int4 v; } pk;                            \
      pk.u[0] = f2b(rv0.x); pk.u[1] = f2b(rv0.y);                           \
      pk.u[2] = f2b(rv0.z); pk.u[3] = f2b(rv0.w);                           \
      pk.u[4] = f2b(rv1.x); pk.u[5] = f2b(rv1.y);                           \
      pk.u[6] = f2b(rv1.z); pk.u[7] = f2b(rv1.w);                           \
      *(int4*)(void*)swz(ldsA, arow, akk) = pk.v;                           \
    } else {                                                                \
      union { unsigned char b[8]; uint2 v2; } in; in.v2 = rae;              \
      union { unsigned short u[8]; int4 v; } pk;                            \
      _Pragma("unroll") for (int q = 0; q < 8; ++q) pk.u[q] = e82b(in.b[q]);\
      *(int4*)(void*)swz(ldsA, arow, akk) = pk.v;                           \
    }                                                                       \
    *(int4*)(void*)swz(ldsB, bn0, akk) = rb0;                               \
    *(int4*)(void*)swz(ldsB, bn1, akk) = rb1;                               \
  }

  LOADG(0);
  for (int k = 0; k < NK; ++k) {
    // barrier A: all waves done reading LDS (lgkm only -- in-flight gloads survive)
    asm volatile("s_waitcnt lgkmcnt(0)" ::: "memory");
    __builtin_amdgcn_s_barrier();
    __builtin_amdgcn_sched_barrier(0);
    WRITELDS();
    __syncthreads();
    if (k + 1 < NK) LOADG((k + 1) * 32);
    bf16x8 af0 = *(const bf16x8*)(void*)swz(ldsA, wr * 32 + lo, hi * 8);
    bf16x8 af1 = *(const bf16x8*)(void*)swz(ldsA, wr * 32 + 16 + lo, hi * 8);
#pragma unroll
    for (int f = 0; f < 8; ++f) {
      bf16x8 bf = *(const bf16x8*)(void*)swz(ldsB, wc * 128 + f * 16 + lo, hi * 8);
      acc[0][f] = __builtin_amdgcn_mfma_f32_16x16x32_bf16(af0, bf, acc[0][f], 0, 0, 0);
      acc[1][f] = __builtin_amdgcn_mfma_f32_16x16x32_bf16(af1, bf, acc[1][f], 0, 0, 0);
    }
  }
  // final barrier before epilogue stage reuse of ldsB
  asm volatile("s_waitcnt lgkmcnt(0)" ::: "memory");
  __builtin_amdgcn_s_barrier();
  __builtin_amdgcn_sched_barrier(0);

  // ---- staged epilogue: 4 chunks of 64 columns ----
#pragma unroll
  for (int cc = 0; cc < 4; ++cc) {
    if (cc) __syncthreads();  // protect stage reuse
    if (wc == (cc >> 1)) {
#pragma unroll
      for (int m = 0; m < 2; ++m) {
        const int rb = wr * 32 + m * 16 + hi * 4;
#pragma unroll
        for (int fl = 0; fl < 4; ++fl) {
          const int f = (cc & 1) * 4 + fl;
          const int c = wc * 128 + f * 16 + lo;  // global column
          float a_ = epia[c], b_ = epib[c];
#pragma unroll
          for (int j = 0; j < 4; ++j) {
            int row = rb + j;
            int r = m0 + row;
            float y = fmaxf(a_ * acc[m][f][j] + b_, 0.f);
            float sv;
            if constexpr (EPI == 1) {
              float dnv = (r < NN) ? dnp[r] : 0.f;
              sv = y * dnv;
            } else {
              sv = y;
            }
            *(unsigned short*)swzst(ldsB, row, (fl * 16 + lo) * 2) = f2b(sv);
          }
        }
      }
    }
    __syncthreads();
    // coalesced store phase: 2 passes x 64 rows, 8 threads/row, 16B (8 bf16) each
#pragma unroll
    for (int pass = 0; pass < 2; ++pass) {
      int rr = pass * 64 + (t >> 3);
      int r = m0 + rr;
      int cb = (t & 7) * 16;
      uint4 v = *(const uint4*)swzst(ldsB, rr, cb);
      if (r < NN) {
        size_t gix = (size_t)r * HID + cc * 64 + (t & 7) * 8;
        union { unsigned short u[8]; uint4 v4; } sb; sb.v4 = v;
        if constexpr (EPI == 0) {
          *(uint4*)((unsigned short*)outv + gix) = v;
          float d = dnp[r];
          union { unsigned char b[8]; uint2 v2; } o8;
#pragma unroll
          for (int q = 0; q < 8; ++q) o8.b[q] = f2e8(d * b2f(sb.u[q]));
          *(uint2*)((unsigned char*)outv2 + gix) = o8.v2;
        } else if constexpr (EPI == 1) {
          union { unsigned char b[8]; uint2 v2; } pv;
          pv.v2 = *(const uint2*)((const unsigned char*)prevv + gix);
          union { unsigned char b[8]; uint2 v2; } o8;
#pragma unroll
          for (int q = 0; q < 8; ++q) o8.b[q] = f2e8(b2f(sb.u[q]) + e82f(pv.b[q]));
          *(uint2*)((unsigned char*)outv + gix) = o8.v2;
        } else {  // EPI == 3
          union { unsigned short u[8]; uint4 v4; } pv;
          pv.v4 = *(const uint4*)((const unsigned short*)prevv + gix);
          union { unsigned short u[8]; uint4 v4; } o;
#pragma unroll
          for (int q = 0; q < 8; ++q) o.u[q] = f2b(b2f(sb.u[q]) + b2f(pv.u[q]));
          *(uint4*)((unsigned short*)outv + gix) = o.v4;
        }
      }
    }
  }
#undef LOADG
#undef WRITELDS
}

// ---------------- classifier GEMM (64x48 tile) on h2 bf16 ----------------
__global__ __launch_bounds__(256) void k_gemmclf(const unsigned short* __restrict__ Av,
                                                 const unsigned short* __restrict__ Bt,
                                                 const float* __restrict__ clfb,
                                                 float* __restrict__ out) {
  __shared__ unsigned short ldsA[64 * 32];
  __shared__ unsigned short ldsB[48 * 32];
  const int t = threadIdx.x;
  const int w = t >> 6, lane = t & 63;
  const int lo = lane & 15, hi = lane >> 4;
  const int m0 = blockIdx.x * 64;
  f32x4 acc[3];
#pragma unroll
  for (int f = 0; f < 3; ++f) acc[f] = (f32x4){0.f, 0.f, 0.f, 0.f};
  const int arow = t >> 2;
  const int akk = (t & 3) * 8;
  const int rg = m0 + arow;
  for (int k0 = 0; k0 < HID; k0 += 32) {
    int4 v = {0, 0, 0, 0};
    if (rg < NN) v = *(const int4*)(Av + (size_t)rg * HID + k0 + akk);
    *(int4*)(void*)swz(ldsA, arow, akk) = v;
    if (t < 48 * 4) {
      int n = t >> 2;
      int4 vb = *(const int4*)(Bt + (size_t)n * HID + k0 + akk);
      *(int4*)(void*)swz(ldsB, n, akk) = vb;
    }
    __syncthreads();
    bf16x8 af = *(const bf16x8*)(void*)swz(ldsA, w * 16 + lo, hi * 8);
#pragma unroll
    for (int f = 0; f < 3; ++f) {
      bf16x8 bf = *(const bf16x8*)(void*)swz(ldsB, f * 16 + lo, hi * 8);
      acc[f] = __builtin_amdgcn_mfma_f32_16x16x32_bf16(af, bf, acc[f], 0, 0, 0);
    }
    __syncthreads();
  }
  const int rbase = m0 + w * 16 + hi * 4;
#pragma unroll
  for (int f = 0; f < 3; ++f) {
    int c = f * 16 + lo;
    if (c >= NOUT) continue;
    float bb = clfb[c];
#pragma unroll
    for (int j = 0; j < 4; ++j) {
      int r = rbase + j;
      if (r < NN) out[(size_t)r * NOUT + c] = acc[f][j] + bb;
    }
  }
}

// ---------------- aggregation: 3-stage pipelined paired-edge e4m4 gather ----------------
// wave = 1 node. Lanes 0-31: even edges, 32-63: odd edges; 8B = 8 feats/lane (256B/row).
// Decode: raw += uf((byte<<19)&0x07F80000); final scale by dn[i]*2^120. Output e4m4.
__global__ __launch_bounds__(256) void k_agg(const int* __restrict__ colptr,
                                             const int* __restrict__ csr,
                                             const float* __restrict__ dn,
                                             const unsigned char* __restrict__ hs,
                                             unsigned char* __restrict__ X) {
  int w = threadIdx.x >> 6, lane = threadIdx.x & 63;
  int i = blockIdx.x * 4 + w;
  int hl = lane & 31, half = lane >> 5;
  const unsigned char* hb = hs + hl * 8;
  int e0 = colptr[i], e1 = colptr[i + 1];
  float a0 = 0, a1 = 0, a2 = 0, a3 = 0, a4 = 0, a5 = 0, a6 = 0, a7 = 0;
  int rA[4], rB[4];
  uint2 vA[4], vB[4];

#define LOADIDX(e_, r_) { \
  _Pragma("unroll") for (int u = 0; u < 4; ++u) { \
    int ee = (e_) + 2 * u + half; \
    int rr = csr[ee]; \
    r_[u] = (ee < e1) ? rr : NN; } }
#define GATHER(r_, v_) { \
  _Pragma("unroll") for (int u = 0; u < 4; ++u) \
    v_[u] = *(const uint2*)(hb + (size_t)r_[u] * HID); }
#define ACCUM(v_) { \
  _Pragma("unroll") for (int u = 0; u < 4; ++u) { \
    a0 += uf((v_[u].x << 19) & 0x07F80000u); a1 += uf((v_[u].x << 11) & 0x07F80000u); \
    a2 += uf((v_[u].x << 3)  & 0x07F80000u); a3 += uf((v_[u].x >> 5)  & 0x07F80000u); \
    a4 += uf((v_[u].y << 19) & 0x07F80000u); a5 += uf((v_[u].y << 11) & 0x07F80000u); \
    a6 += uf((v_[u].y << 3)  & 0x07F80000u); a7 += uf((v_[u].y >> 5)  & 0x07F80000u); } }

  int nb = (e1 - e0 + 7) >> 3;
  if (nb == 1) {
    LOADIDX(e0, rA); GATHER(rA, vA); ACCUM(vA);
  } else if (nb > 1) {
    LOADIDX(e0, rA);
    GATHER(rA, vA);
    LOADIDX(e0 + 8, rB);
    int b = 1, e = e0 + 8;
    for (; b + 1 < nb; ++b, e += 8) {
      if (b & 1) { GATHER(rB, vB); LOADIDX(e + 8, rA); ACCUM(vA); }
      else       { GATHER(rA, vA); LOADIDX(e + 8, rB); ACCUM(vB); }
    }
    if (b & 1) { GATHER(rB, vB); ACCUM(vA); ACCUM(vB); }
    else       { GATHER(rA, vA); ACCUM(vB); ACCUM(vA); }
  }
  // merge even/odd halves (lane ^ 32 holds same features)
  a0 += __shfl_xor(a0, 32); a1 += __shfl_xor(a1, 32);
  a2 += __shfl_xor(a2, 32); a3 += __shfl_xor(a3, 32);
  a4 += __shfl_xor(a4, 32); a5 += __shfl_xor(a5, 32);
  a6 += __shfl_xor(a6, 32); a7 += __shfl_xor(a7, 32);
  if (half == 0) {
    float d = dn[i] * 0x1p120f;  // fold e4m4 rescale into dn
    union { unsigned char b[8]; uint2 v; } o;
    o.b[0] = f2e8(d * a0); o.b[1] = f2e8(d * a1); o.b[2] = f2e8(d * a2); o.b[3] = f2e8(d * a3);
    o.b[4] = f2e8(d * a4); o.b[5] = f2e8(d * a5); o.b[6] = f2e8(d * a6); o.b[7] = f2e8(d * a7);
    *(uint2*)(X + (size_t)i * HID + hl * 8) = o.v;
  }
}

extern "C" void kernel_launch(void* const* d_in, const int* in_sizes, int n_in,
                              void* d_out, int out_size, void* d_ws, size_t ws_size,
                              hipStream_t stream) {
  const float* x        = (const float*)d_in[0];
  const int*   edge     = (const int*)d_in[1];
  const int*   erow     = edge;
  const int*   ecol     = edge + NE;
  const float* fc0_W    = (const float*)d_in[2];
  const float* fc0_b    = (const float*)d_in[3];
  const float* conv_W   = (const float*)d_in[4];
  const float* conv_b   = (const float*)d_in[5];
  const float* bn_gamma = (const float*)d_in[6];
  const float* bn_beta  = (const float*)d_in[7];
  const float* bn_mean  = (const float*)d_in[8];
  const float* bn_var   = (const float*)d_in[9];
  const float* clf_W    = (const float*)d_in[10];
  const float* clf_b    = (const float*)d_in[11];

  char* p = (char*)d_ws;
  auto alloc = [&](size_t bytes) { char* r = p; p += (bytes + 255) & ~(size_t)255; return r; };
  int*   deg      = (int*)alloc((size_t)NN * 4);
  float* dn       = (float*)alloc((size_t)NN * 4);
  int*   colptr   = (int*)alloc((size_t)(NN + 1) * 4);
  int*   pos      = (int*)alloc((size_t)NN * 4);
  int*   partials = (int*)alloc(1024);
  int*   bcnt     = (int*)alloc(NB2 * 4);
  int*   bbase    = (int*)alloc(NB2 * 4);
  int*   cursor   = (int*)alloc(NB2 * 4);
  int*   csr_row  = (int*)alloc(((size_t)NE + 16) * 4);
  unsigned short* W0t   = (unsigned short*)alloc((size_t)256 * 512 * 2);
  unsigned short* Wct   = (unsigned short*)alloc((size_t)2 * 256 * 256 * 2);
  unsigned short* Wclft = (unsigned short*)alloc((size_t)48 * 256 * 2);
  float* epia = (float*)alloc(768 * 4);
  float* epib = (float*)alloc(768 * 4);
  unsigned short* h0  = (unsigned short*)alloc((size_t)NN * HID * 2);      // bf16; becomes h2 in-place
  unsigned char*  h0s = (unsigned char*)alloc((size_t)(NN + 1) * HID);     // e4m4 (+zero row NN); becomes h1s
  unsigned char*  X   = (unsigned char*)alloc((size_t)NN * HID);           // agg output (e4m4)
  unsigned int* ebuf = (unsigned int*)X;  // alias: ebuf (12.8MB) dead before X (25.6MB) first written

  int nbBlk = (NE + EPB - 1) / EPB;  // 391
  hipMemsetAsync(bcnt, 0, NB2 * 4, stream);
  k_bhist<<<nbBlk, 256, 0, stream>>>(ecol, bcnt);
  k_bscan<<<1, 256, 0, stream>>>(bcnt, bbase, cursor);
  k_bucket<<<nbBlk, 256, 0, stream>>>(erow, ecol, cursor, ebuf);
  k_subdeg<<<NBKT, 256, 0, stream>>>(ebuf, bbase, bcnt, deg, dn);
  int nb = (NN + SCAN_CH - 1) / SCAN_CH;  // 98
  k_scan_part<<<nb, 256, 0, stream>>>(deg, partials);
  k_scan_partials<<<1, 128, 0, stream>>>(partials, nb);
  k_scan_final<<<nb, 256, 0, stream>>>(deg, partials, colptr, pos);
  k_fill2<<<NBKT * 4, 256, 0, stream>>>(ebuf, bbase, bcnt, pos, csr_row);
  k_prep<<<1076, 256, 0, stream>>>(fc0_W, fc0_b, conv_W, conv_b, bn_gamma, bn_beta,
                                   bn_mean, bn_var, clf_W, W0t, Wct, Wclft, epia, epib, h0s);

  int gm2 = (NN + 127) / 128;  // 782
  // fc0 + BN0 + ReLU -> h0 (bf16) + h0s (e4m4, dn-scaled)
  k_gemm2<KIN, 0, 0><<<gm2, 512, 0, stream>>>(x, W0t, epia, epib, nullptr, dn, h0, h0s);
  // layer 0: agg(h0s) -> X (e4m4); gemm: scaled residual, in-place h0s -> h1s (e4m4)
  k_agg<<<(NN + 3) / 4, 256, 0, stream>>>(colptr, csr_row, dn, h0s, X);
  k_gemm2<HID, 2, 1><<<gm2, 512, 0, stream>>>(X, Wct, epia + 256, epib + 256, h0s, dn, h0s, nullptr);
  // layer 1: agg(h1s) -> X (e4m4); gemm: unscaled residual, in-place h0 -> h2 (bf16)
  k_agg<<<(NN + 3) / 4, 256, 0, stream>>>(colptr, csr_row, dn, h0s, X);
  k_gemm2<HID, 2, 3><<<gm2, 512, 0, stream>>>(X, Wct + 65536, epia + 512, epib + 512, h0, nullptr, h0, nullptr);
  // classifier -> f32 out
  k_gemmclf<<<(NN + 63) / 64, 256, 0, stream>>>(h0, Wclft, clf_b, (float*)d_out);
}